// Round 16
// baseline (210.496 us; speedup 1.0000x reference)
//
#include <hip/hip_runtime.h>
#include <hip/hip_bf16.h>

typedef __attribute__((ext_vector_type(4))) int i32x4;
typedef __attribute__((ext_vector_type(8))) int i32x8;
typedef __attribute__((ext_vector_type(16))) float f32x16;

#define GLOBAL_CPTR(x) ((__attribute__((address_space(1))) const void*)(x))
#define LDS_PTR(x)     ((__attribute__((address_space(3))) void*)(x))

// ---------------------------------------------------------------------------
// MXFP4 quantize (merged x+w, one launch) — AT HBM ROOF (6.3 TB/s), frozen.
// ---------------------------------------------------------------------------
__global__ __launch_bounds__(256) void mxfp4_quant_pack_kernel(
    const float* __restrict__ xin, unsigned char* __restrict__ xq,
    unsigned char* __restrict__ xsc, const float* __restrict__ win,
    unsigned char* __restrict__ wq, unsigned char* __restrict__ wsc,
    int kshift, int gx) {
  const int KC = 1 << (kshift - 5);   // 32-elem chunks per row
  const int CQ = KC >> 2;             // chunk-quads per row (pow2)
  const int bid0 = blockIdx.x;
  const float* in;
  unsigned char* outq;
  unsigned char* outsc;
  int bid;
  if (bid0 < gx) { in = xin; outq = xq; outsc = xsc; bid = bid0; }
  else           { in = win; outq = wq; outsc = wsc; bid = bid0 - gx; }

  const int cq  = bid & (CQ - 1);     // 128-k span
  const int R   = (bid >> (kshift - 7)) << 6;  // 64-row block base
  const int t   = threadIdx.x;

  __shared__ float sf[64 * 132];      // 33 KB, row stride 132 (pad 4)

  const float* base = in + ((size_t)R << kshift) + (cq << 7);
#pragma unroll
  for (int i = 0; i < 8; ++i) {
    const int g   = i * 256 + t;      // float4 index 0..2047
    const int row = g >> 5;           // 32 float4 per row
    const int c4  = g & 31;
    float4 v = *reinterpret_cast<const float4*>(
        base + ((size_t)row << kshift) + (c4 << 2));
    *reinterpret_cast<float4*>(sf + row * 132 + (c4 << 2)) = v;
  }
  __syncthreads();

  const int rl = (t & 3) + ((t >> 4) << 2);   // 0..63
  const int kc = (t >> 2) & 3;                // 0..3
  const float* src = sf + rl * 132 + (kc << 5);
  float v[32];
#pragma unroll
  for (int i = 0; i < 8; ++i)
    *reinterpret_cast<float4*>(v + 4 * i) =
        *reinterpret_cast<const float4*>(src + 4 * i);

  float am = 0.f;
#pragma unroll
  for (int j = 0; j < 32; ++j) am = fmaxf(am, fabsf(v[j]));

  const float safe = am > 0.f ? am : 1.f;
  const int se = ilogbf(safe) - 2;    // floor(log2(amax)) - E2M1_EMAX
  const float inv = ldexpf(1.f, -se);

  unsigned int packs[4] = {0, 0, 0, 0};
#pragma unroll
  for (int j = 0; j < 32; ++j) {
    const float val = v[j] * inv;              // exact (power-of-2)
    const float av = fabsf(val);
    const float avc = fmaxf(av, 9.765625e-4f); // 2^-10 floor
    int ee = (int)((__float_as_uint(avc) >> 23) & 0xFF) - 127;
    ee = ee < 0 ? 0 : (ee > 2 ? 2 : ee);
    const float istep = __uint_as_float((unsigned)(128 - ee) << 23); // 2^(1-ee)
    const int m = (int)rintf(av * istep);      // exact small int
    unsigned int c = (unsigned)(m + (ee << 1));
    c = c > 7u ? 7u : c;
    c |= (__float_as_uint(val) >> 28) & 8u;    // sign bit -> bit3
    packs[j >> 3] |= c << (4 * (j & 7));
  }

  const int row = R + rl;
  const size_t chunk = (size_t)(row >> 8) * KC + (cq << 2) + kc;
  *reinterpret_cast<uint4*>(outq + chunk * 4096 + (size_t)(row & 255) * 16) =
      make_uint4(packs[0], packs[1], packs[2], packs[3]);
  outsc[chunk * 256 + (row & 31) * 8 + ((row >> 5) & 7)] =
      (unsigned char)(se + 127);
}

// ---------------------------------------------------------------------------
// MX-FP4 scaled GEMM: C = dequant(A)*dequant(B)^T + bias.
// R16 = R15 (4-wave WG, 128x256 tile, per-wave 128x64) with scales moved
// OUT of LDS: per-lane direct global loads (L3-resident), prefetched one
// K-tile ahead into ping-pong regs.  Buffer shrinks 26624->24576B, dbuf
// 48KB -> 3 WGs/CU = 144KB (R15 measured Occ 23%: 2x53248+reserve broke
// the 160KB pool; the 3rd WG never resided, so the decoupling never ran).
// Scales via OPSEL byte-select.  A half-panel select via (bm&1).
// LDS/buf 24576B: [A 8KB][B 16KB @8192].
// ---------------------------------------------------------------------------
#define BM 128
#define BN 256
#define NTHR 256
#define BUFS 24576

__global__ __launch_bounds__(NTHR, 3) void mxfp_gemm_kernel(
    const unsigned char* __restrict__ Aq, const unsigned char* __restrict__ Asc,
    const unsigned char* __restrict__ Bq, const unsigned char* __restrict__ Bsc,
    const float* __restrict__ bias, float* __restrict__ C,
    int M, int N, int K) {
  __shared__ unsigned char lds[2 * BUFS];  // 48 KiB

  const int tid = threadIdx.x;
  const int l   = tid & 63;
  const int wid = tid >> 6;   // 0..3
  const int wn  = wid;        // all waves split N; each owns 128x64

  const int nwg = gridDim.x;       // 1024, multiple of 8
  const int bid = blockIdx.x;
  const int swz = (bid & 7) * (nwg >> 3) + (bid >> 3);
  const int nbn = N / BN;          // 16
  const int bm  = swz / nbn;       // 0..63 (128-row panel)
  const int bn  = swz % nbn;

  const int KC = K >> 5;  // 16B-chunks per row

  f32x16 acc[4][2] = {};
  int sa_a[2], sb_a[2], sa_b[2], sb_b[2];  // scale ping-pong (1 tile ahead)

// stage one K-tile: per wave 2 A-data + 4 B-data DMAs (uniform 6).
#define STAGE(BUFO, KT)                                                        \
  do {                                                                         \
    const size_t t4 = (size_t)(KT) * 4;                                        \
    const size_t abase =                                                       \
        ((size_t)(bm >> 1) * KC + t4 + wid) * 4096 + ((bm & 1) << 11);         \
    _Pragma("unroll") for (int h = 0; h < 2; ++h)                              \
      __builtin_amdgcn_global_load_lds(                                        \
          GLOBAL_CPTR(Aq + abase + h * 1024 + (l << 4)),                       \
          LDS_PTR(lds + (BUFO) + wid * 2048 + h * 1024), 16, 0, 0);            \
    _Pragma("unroll") for (int c = 0; c < 4; ++c)                              \
      __builtin_amdgcn_global_load_lds(                                        \
          GLOBAL_CPTR(Bq + ((size_t)bn * KC + t4 + c) * 4096 + (wid << 10) +   \
                      (l << 4)),                                               \
          LDS_PTR(lds + (BUFO) + 8192 + c * 4096 + (wid << 10)), 16, 0, 0);    \
  } while (0)

// prefetch scales for K-tile KT into reg pair (SA, SB): per-lane direct
// global loads (chunk cc = 2*ks + (l>>5)); L3-resident, latency covered by
// the intervening tile's compute before the vmcnt(0) drain.
#define LOADSC(SA, SB, KT)                                                     \
  do {                                                                         \
    _Pragma("unroll") for (int ks = 0; ks < 2; ++ks) {                         \
      const size_t cc = (size_t)(KT) * 4 + (ks << 1) + (l >> 5);               \
      SA[ks] = *(const int*)(Asc + ((size_t)(bm >> 1) * KC + cc) * 256 +       \
                             ((l & 31) << 3) + ((bm & 1) << 2));               \
      SB[ks] = *(const ushort*)(Bsc + ((size_t)bn * KC + cc) * 256 +           \
                                ((l & 31) << 3) + (wn << 1));                  \
    }                                                                          \
  } while (0)

// one MFMA with literal opsel byte indices (required: constant integer args)
#define MFMA1(MB, NB, AV, BV)                                                  \
  acc[MB][NB] = __builtin_amdgcn_mfma_scale_f32_32x32x64_f8f6f4(               \
      a8[MB], b8[NB], acc[MB][NB], 4, 4, MB, AV, NB, BV)

// compute one K-tile from buffer BUFO using prefetched scale regs SA/SB.
#define KTILE(BUFO, SA, SB)                                                    \
  do {                                                                         \
    const i32x4 z4 = {0, 0, 0, 0};                                             \
    _Pragma("unroll") for (int ks = 0; ks < 2; ++ks) {                         \
      const int cofsA = (ks << 12) + ((l & 32) << 6);  /* chunk*2048 */        \
      const int cofsB = (ks << 13) + ((l & 32) << 7);  /* chunk*4096 */        \
      i32x8 a8[4], b8[2];                                                      \
      _Pragma("unroll") for (int mb = 0; mb < 4; ++mb)                         \
        a8[mb] = __builtin_shufflevector(                                      \
            *(const i32x4*)(lds + (BUFO) + cofsA +                             \
                            (((mb << 5) + (l & 31)) << 4)),                    \
            z4, 0, 1, 2, 3, 4, 5, 6, 7);                                       \
      _Pragma("unroll") for (int nb = 0; nb < 2; ++nb)                         \
        b8[nb] = __builtin_shufflevector(                                      \
            *(const i32x4*)(lds + (BUFO) + 8192 + cofsB +                      \
                            (((wn << 6) + (nb << 5) + (l & 31)) << 4)),        \
            z4, 0, 1, 2, 3, 4, 5, 6, 7);                                       \
      MFMA1(0, 0, SA[ks], SB[ks]); MFMA1(0, 1, SA[ks], SB[ks]);                \
      MFMA1(1, 0, SA[ks], SB[ks]); MFMA1(1, 1, SA[ks], SB[ks]);                \
      MFMA1(2, 0, SA[ks], SB[ks]); MFMA1(2, 1, SA[ks], SB[ks]);                \
      MFMA1(3, 0, SA[ks], SB[ks]); MFMA1(3, 1, SA[ks], SB[ks]);                \
    }                                                                          \
  } while (0)

  // prologue: tile0 data -> buf0, tile0 scales -> set A
  STAGE(0, 0);
  LOADSC(sa_a, sb_a, 0);
  asm volatile("s_waitcnt vmcnt(0)" ::: "memory");
  __builtin_amdgcn_s_barrier();
  asm volatile("" ::: "memory");

  const int NKT = K >> 7;  // 128-wide K-tiles (even)
  for (int t = 0; t < NKT; t += 2) {
    const int t1 = t + 1;                          // valid (NKT even)
    const int t2 = (t + 2 < NKT) ? (t + 2) : t;   // clamp -> dead buffer
    // tile t: compute buf0 + scale set A; stage t+1 -> buf1, scales -> set B
    STAGE(BUFS, t1);
    LOADSC(sa_b, sb_b, t1);
    KTILE(0, sa_a, sb_a);
    asm volatile("s_waitcnt vmcnt(0)" ::: "memory");
    __builtin_amdgcn_s_barrier();
    asm volatile("" ::: "memory");
    // tile t+1: compute buf1 + scale set B; stage t+2 -> buf0, scales -> A
    STAGE(0, t2);
    LOADSC(sa_a, sb_a, t2);
    KTILE(BUFS, sa_b, sb_b);
    asm volatile("s_waitcnt vmcnt(0)" ::: "memory");
    __builtin_amdgcn_s_barrier();
    asm volatile("" ::: "memory");
  }

  // epilogue: 32x32 C/D layout: col=lane&31, row=(reg&3)+8*(reg>>2)+4*(l>>5)
  const int colb = bn * BN + wn * 64 + (l & 31);
  const int rowb = bm * BM + ((l >> 5) << 2);
  const float bv0 = bias[colb];
  const float bv1 = bias[colb + 32];
#pragma unroll
  for (int mb = 0; mb < 4; ++mb) {
#pragma unroll
    for (int nb = 0; nb < 2; ++nb) {
      const float bv = nb ? bv1 : bv0;
      const int col = colb + nb * 32;
#pragma unroll
      for (int r = 0; r < 16; ++r) {
        const int row = rowb + mb * 32 + ((r >> 2) << 3) + (r & 3);
        C[(size_t)row * N + col] = acc[mb][nb][r] + bv;
      }
    }
  }
}

// ---------------------------------------------------------------------------
extern "C" void kernel_launch(void* const* d_in, const int* in_sizes, int n_in,
                              void* d_out, int out_size, void* d_ws, size_t ws_size,
                              hipStream_t stream) {
  const float* x    = (const float*)d_in[0];  // [B,S,K] = [M,K]
  const float* w    = (const float*)d_in[1];  // [N,K]
  const float* bias = (const float*)d_in[2];  // [N]
  float* out = (float*)d_out;

  const int N = in_sizes[2];
  const int K = in_sizes[1] / N;
  const int M = (int)((long long)in_sizes[0] / K);
  const int kshift = __builtin_ctz(K);

  unsigned char* xq  = (unsigned char*)d_ws;               // M*K/2
  unsigned char* wq  = xq + ((size_t)M * K >> 1);          // N*K/2
  unsigned char* xsc = wq + ((size_t)N * K >> 1);          // M*K/32
  unsigned char* wsc = xsc + ((size_t)M * K >> 5);         // N*K/32

  const int CQ = (K >> 5) >> 2;  // chunk-quads per row
  const int gx = (M >> 6) * CQ;
  const int gw = (N >> 6) * CQ;

  mxfp4_quant_pack_kernel<<<dim3((unsigned)(gx + gw)), dim3(256), 0, stream>>>(
      x, xq, xsc, w, wq, wsc, kshift, gx);

  dim3 grid((M / BM) * (N / BN));
  mxfp_gemm_kernel<<<grid, dim3(NTHR), 0, stream>>>(xq, xsc, wq, wsc, bias, out,
                                                    M, N, K);
}

// Round 17
// 135.051 us; speedup vs baseline: 1.5586x; 1.5586x over previous
//
#include <hip/hip_runtime.h>
#include <hip/hip_bf16.h>

typedef __attribute__((ext_vector_type(4))) int i32x4;
typedef __attribute__((ext_vector_type(8))) int i32x8;
typedef __attribute__((ext_vector_type(16))) float f32x16;

#define GLOBAL_CPTR(x) ((__attribute__((address_space(1))) const void*)(x))
#define LDS_PTR(x)     ((__attribute__((address_space(3))) void*)(x))

// ---------------------------------------------------------------------------
// MXFP4 quantize (merged x+w, one launch) — AT HBM ROOF (6.3 TB/s).
// Block = 64 rows x 128 k. Phase 1: coalesced float4 loads into padded LDS.
// Phase 2: one thread = one full 32-elem MXFP block; quads write full 64B
// lines. Layout: chunk=(row>>8)*(K/32)+(k>>5); data=chunk*4096+(row&255)*16;
// scale byte = chunk*256+(row&31)*8+((row>>5)&7).
// ---------------------------------------------------------------------------
__global__ __launch_bounds__(256) void mxfp4_quant_pack_kernel(
    const float* __restrict__ xin, unsigned char* __restrict__ xq,
    unsigned char* __restrict__ xsc, const float* __restrict__ win,
    unsigned char* __restrict__ wq, unsigned char* __restrict__ wsc,
    int kshift, int gx) {
  const int KC = 1 << (kshift - 5);   // 32-elem chunks per row
  const int CQ = KC >> 2;             // chunk-quads per row (pow2)
  const int bid0 = blockIdx.x;
  const float* in;
  unsigned char* outq;
  unsigned char* outsc;
  int bid;
  if (bid0 < gx) { in = xin; outq = xq; outsc = xsc; bid = bid0; }
  else           { in = win; outq = wq; outsc = wsc; bid = bid0 - gx; }

  const int cq  = bid & (CQ - 1);     // 128-k span
  const int R   = (bid >> (kshift - 7)) << 6;  // 64-row block base
  const int t   = threadIdx.x;

  __shared__ float sf[64 * 132];      // 33 KB, row stride 132 (pad 4)

  const float* base = in + ((size_t)R << kshift) + (cq << 7);
#pragma unroll
  for (int i = 0; i < 8; ++i) {
    const int g   = i * 256 + t;      // float4 index 0..2047
    const int row = g >> 5;           // 32 float4 per row
    const int c4  = g & 31;
    float4 v = *reinterpret_cast<const float4*>(
        base + ((size_t)row << kshift) + (c4 << 2));
    *reinterpret_cast<float4*>(sf + row * 132 + (c4 << 2)) = v;
  }
  __syncthreads();

  const int rl = (t & 3) + ((t >> 4) << 2);   // 0..63
  const int kc = (t >> 2) & 3;                // 0..3
  const float* src = sf + rl * 132 + (kc << 5);
  float v[32];
#pragma unroll
  for (int i = 0; i < 8; ++i)
    *reinterpret_cast<float4*>(v + 4 * i) =
        *reinterpret_cast<const float4*>(src + 4 * i);

  float am = 0.f;
#pragma unroll
  for (int j = 0; j < 32; ++j) am = fmaxf(am, fabsf(v[j]));

  const float safe = am > 0.f ? am : 1.f;
  const int se = ilogbf(safe) - 2;    // floor(log2(amax)) - E2M1_EMAX
  const float inv = ldexpf(1.f, -se);

  unsigned int packs[4] = {0, 0, 0, 0};
#pragma unroll
  for (int j = 0; j < 32; ++j) {
    const float val = v[j] * inv;              // exact (power-of-2)
    const float av = fabsf(val);
    const float avc = fmaxf(av, 9.765625e-4f); // 2^-10 floor
    int ee = (int)((__float_as_uint(avc) >> 23) & 0xFF) - 127;
    ee = ee < 0 ? 0 : (ee > 2 ? 2 : ee);
    const float istep = __uint_as_float((unsigned)(128 - ee) << 23); // 2^(1-ee)
    const int m = (int)rintf(av * istep);      // exact small int
    unsigned int c = (unsigned)(m + (ee << 1));
    c = c > 7u ? 7u : c;
    c |= (__float_as_uint(val) >> 28) & 8u;    // sign bit -> bit3
    packs[j >> 3] |= c << (4 * (j & 7));
  }

  const int row = R + rl;
  const size_t chunk = (size_t)(row >> 8) * KC + (cq << 2) + kc;
  *reinterpret_cast<uint4*>(outq + chunk * 4096 + (size_t)(row & 255) * 16) =
      make_uint4(packs[0], packs[1], packs[2], packs[3]);
  outsc[chunk * 256 + (row & 31) * 8 + ((row >> 5) & 7)] =
      (unsigned char)(se + 127);
}

// ---------------------------------------------------------------------------
// MX-FP4 scaled GEMM: C = dequant(A)*dequant(B)^T + bias  (R15 = best: 89.8us)
// WG = 4 waves (256 thr), tile 128x256, per-wave output 128x64, LDS 52KB.
// Bit-exact to reference (absmax 0.0): mfma_scale_f32_32x32x64_f8f6f4,
// FMT=4 E2M1, E8M0 block scales via OPSEL byte-select immediates.
// Family ceiling notes (16 rounds): 8 structural variants land 88-103us;
// quant at HBM roof; GEMM at 3124 TF = 34% fp4 dense peak, above the m153
// reference point; residual is barrier-coupled latency at 2 waves/SIMD.
// LDS/buf 26624B: [A 8KB][B 16KB @8192][Asc 1KB @24576][Bsc 1KB @25600].
// ---------------------------------------------------------------------------
#define BM 128
#define BN 256
#define NTHR 256
#define BUFS 26624

__global__ __launch_bounds__(NTHR, 3) void mxfp_gemm_kernel(
    const unsigned char* __restrict__ Aq, const unsigned char* __restrict__ Asc,
    const unsigned char* __restrict__ Bq, const unsigned char* __restrict__ Bsc,
    const float* __restrict__ bias, float* __restrict__ C,
    int M, int N, int K) {
  __shared__ unsigned char lds[2 * BUFS];  // 52 KiB

  const int tid = threadIdx.x;
  const int l   = tid & 63;
  const int wid = tid >> 6;   // 0..3
  const int wn  = wid;        // all waves split N; each owns 128x64

  const int nwg = gridDim.x;       // 1024, multiple of 8
  const int bid = blockIdx.x;
  const int swz = (bid & 7) * (nwg >> 3) + (bid >> 3);
  const int nbn = N / BN;          // 16
  const int bm  = swz / nbn;       // 0..63 (128-row panel)
  const int bn  = swz % nbn;

  const int KC = K >> 5;  // 16B-chunks per row

  f32x16 acc[4][2] = {};

// stage one K-tile: per wave 2 A-data + 4 B-data + 2 scale DMAs (uniform 8).
#define STAGE(BUFO, KT)                                                        \
  do {                                                                         \
    const size_t t4 = (size_t)(KT) * 4;                                        \
    const size_t abase =                                                       \
        ((size_t)(bm >> 1) * KC + t4 + wid) * 4096 + ((bm & 1) << 11);         \
    _Pragma("unroll") for (int h = 0; h < 2; ++h)                              \
      __builtin_amdgcn_global_load_lds(                                        \
          GLOBAL_CPTR(Aq + abase + h * 1024 + (l << 4)),                       \
          LDS_PTR(lds + (BUFO) + wid * 2048 + h * 1024), 16, 0, 0);            \
    _Pragma("unroll") for (int c = 0; c < 4; ++c)                              \
      __builtin_amdgcn_global_load_lds(                                        \
          GLOBAL_CPTR(Bq + ((size_t)bn * KC + t4 + c) * 4096 + (wid << 10) +   \
                      (l << 4)),                                               \
          LDS_PTR(lds + (BUFO) + 8192 + c * 4096 + (wid << 10)), 16, 0, 0);    \
    __builtin_amdgcn_global_load_lds(                                          \
        GLOBAL_CPTR(Asc + ((size_t)(bm >> 1) * KC + t4 + wid) * 256 +          \
                    (l << 2)),                                                 \
        LDS_PTR(lds + (BUFO) + 24576 + (wid << 8)), 4, 0, 0);                  \
    __builtin_amdgcn_global_load_lds(                                          \
        GLOBAL_CPTR(Bsc + ((size_t)bn * KC + t4 + wid) * 256 + (l << 2)),      \
        LDS_PTR(lds + (BUFO) + 25600 + (wid << 8)), 4, 0, 0);                  \
  } while (0)

// one MFMA with literal opsel byte indices (required: constant integer args)
#define MFMA1(MB, NB, AV, BV)                                                  \
  acc[MB][NB] = __builtin_amdgcn_mfma_scale_f32_32x32x64_f8f6f4(               \
      a8[MB], b8[NB], acc[MB][NB], 4, 4, MB, AV, NB, BV)

// compute one K-tile: per ks-half 4 A + 2 B frag reads + 2 scale reads,
// 8 MFMA with opsel scales.
#define KTILE(BUFO)                                                            \
  do {                                                                         \
    const i32x4 z4 = {0, 0, 0, 0};                                             \
    _Pragma("unroll") for (int ks = 0; ks < 2; ++ks) {                         \
      const int cofsA = (ks << 12) + ((l & 32) << 6);  /* chunk*2048 */        \
      const int cofsB = (ks << 13) + ((l & 32) << 7);  /* chunk*4096 */        \
      const int scofs = (ks << 9) + ((l & 32) << 3);   /* chunk*256  */        \
      i32x8 a8[4], b8[2];                                                      \
      _Pragma("unroll") for (int mb = 0; mb < 4; ++mb)                         \
        a8[mb] = __builtin_shufflevector(                                      \
            *(const i32x4*)(lds + (BUFO) + cofsA +                             \
                            (((mb << 5) + (l & 31)) << 4)),                    \
            z4, 0, 1, 2, 3, 4, 5, 6, 7);                                       \
      _Pragma("unroll") for (int nb = 0; nb < 2; ++nb)                         \
        b8[nb] = __builtin_shufflevector(                                      \
            *(const i32x4*)(lds + (BUFO) + 8192 + cofsB +                      \
                            (((wn << 6) + (nb << 5) + (l & 31)) << 4)),        \
            z4, 0, 1, 2, 3, 4, 5, 6, 7);                                       \
      const int av = *(const int*)(lds + (BUFO) + 24576 + scofs +              \
                                   ((l & 31) << 3) + ((bm & 1) << 2));         \
      const int bv = *(const ushort*)(lds + (BUFO) + 25600 + scofs +           \
                                      ((l & 31) << 3) + (wn << 1));            \
      MFMA1(0, 0, av, bv); MFMA1(0, 1, av, bv);                                \
      MFMA1(1, 0, av, bv); MFMA1(1, 1, av, bv);                                \
      MFMA1(2, 0, av, bv); MFMA1(2, 1, av, bv);                                \
      MFMA1(3, 0, av, bv); MFMA1(3, 1, av, bv);                                \
    }                                                                          \
  } while (0)

  // prologue: tile0 -> buf0
  STAGE(0, 0);
  asm volatile("s_waitcnt vmcnt(0)" ::: "memory");
  __builtin_amdgcn_s_barrier();
  asm volatile("" ::: "memory");

  const int NKT = K >> 7;  // 128-wide K-tiles
  for (int t = 0; t < NKT; ++t) {
    const int tn = (t + 1 < NKT) ? (t + 1) : t;  // clamp -> dead buffer
    const int bufC = (t & 1) ? BUFS : 0;
    const int bufN = (t & 1) ? 0 : BUFS;
    STAGE(bufN, tn);       // 8 DMAs/wave, full compute window to land
    KTILE(bufC);
    asm volatile("s_waitcnt vmcnt(0)" ::: "memory");
    __builtin_amdgcn_s_barrier();
    asm volatile("" ::: "memory");
  }

  // epilogue: 32x32 C/D layout: col=lane&31, row=(reg&3)+8*(reg>>2)+4*(l>>5)
  const int colb = bn * BN + wn * 64 + (l & 31);
  const int rowb = bm * BM + ((l >> 5) << 2);
  const float bv0 = bias[colb];
  const float bv1 = bias[colb + 32];
#pragma unroll
  for (int mb = 0; mb < 4; ++mb) {
#pragma unroll
    for (int nb = 0; nb < 2; ++nb) {
      const float bv = nb ? bv1 : bv0;
      const int col = colb + nb * 32;
#pragma unroll
      for (int r = 0; r < 16; ++r) {
        const int row = rowb + mb * 32 + ((r >> 2) << 3) + (r & 3);
        C[(size_t)row * N + col] = acc[mb][nb][r] + bv;
      }
    }
  }
}

// ---------------------------------------------------------------------------
extern "C" void kernel_launch(void* const* d_in, const int* in_sizes, int n_in,
                              void* d_out, int out_size, void* d_ws, size_t ws_size,
                              hipStream_t stream) {
  const float* x    = (const float*)d_in[0];  // [B,S,K] = [M,K]
  const float* w    = (const float*)d_in[1];  // [N,K]
  const float* bias = (const float*)d_in[2];  // [N]
  float* out = (float*)d_out;

  const int N = in_sizes[2];
  const int K = in_sizes[1] / N;
  const int M = (int)((long long)in_sizes[0] / K);
  const int kshift = __builtin_ctz(K);

  unsigned char* xq  = (unsigned char*)d_ws;               // M*K/2
  unsigned char* wq  = xq + ((size_t)M * K >> 1);          // N*K/2
  unsigned char* xsc = wq + ((size_t)N * K >> 1);          // M*K/32
  unsigned char* wsc = xsc + ((size_t)M * K >> 5);         // N*K/32

  const int CQ = (K >> 5) >> 2;  // chunk-quads per row
  const int gx = (M >> 6) * CQ;
  const int gw = (N >> 6) * CQ;

  mxfp4_quant_pack_kernel<<<dim3((unsigned)(gx + gw)), dim3(256), 0, stream>>>(
      x, xq, xsc, w, wq, wsc, kshift, gx);

  dim3 grid((M / BM) * (N / BN));
  mxfp_gemm_kernel<<<grid, dim3(NTHR), 0, stream>>>(xq, xsc, wq, wsc, bias, out,
                                                    M, N, K);
}